// Round 5
// baseline (124.642 us; speedup 1.0000x reference)
//
#include <hip/hip_runtime.h>
#include <math.h>

#define H 4096
#define D 104
#define NBLK (H / 4)      // 1024 blocks, exactly 4 per CU -> all co-resident
#define NCNT 32
#define CSTRIDE 32        // 32 uints = 128 B between counters (own cache line)

typedef float f32x4 __attribute__((ext_vector_type(4)));

__device__ __forceinline__ float dot4(f32x4 a, f32x4 b) {
    return a.x * b.x + a.y * b.y + a.z * b.z + a.w * b.w;
}

// One fused kernel.
// Phase 1: block b computes h_t rows 4b..4b+3 (Uw stream, hidden in LDS).
//          Blocks 0..103 prefetch their Vw row into registers (overlaps).
// Grid barrier: split atomic counters (all 1024 blocks co-resident by
//          construction: 4 blocks/CU avg, HW capacity 8/CU -> no deadlock).
// Phase 2: blocks 0..103 compute pred[b] = Vw[b,:].h_t + Vb[b].
// Phase 3: last-arriving block per segment does that segment's log_softmax.
__global__ void __launch_bounds__(256, 4) k_fused(
    const float* __restrict__ Uw, const float* __restrict__ hidden,
    const float* __restrict__ Ub, const float* __restrict__ Ww,
    const float* __restrict__ line, const float* __restrict__ Wb,
    const float* __restrict__ Vw, const float* __restrict__ Vb,
    float* __restrict__ out,          // [0:104) logsoft, [104:4200) h_t
    unsigned* __restrict__ cnt,       // 32 counters, 128B stride (zeroed)
    unsigned* __restrict__ segcnt,    // 10 counters, 128B stride (zeroed)
    float* __restrict__ pred)         // 104 entries, 128B stride
{
    __shared__ f32x4 s_h4[H / 4];     // 16 KB
    __shared__ float s_red[4];
    __shared__ int s_last;

    const int tid  = threadIdx.x;
    const int wave = tid >> 6;
    const int lane = tid & 63;
    const int bid  = blockIdx.x;
    const int row  = bid * 4 + wave;

    // stage hidden to LDS (1024 f32x4 / 256 threads)
    const f32x4* __restrict__ hv = (const f32x4*)hidden;
    #pragma unroll
    for (int i = tid; i < H / 4; i += 256)
        s_h4[i] = hv[i];

    // prefetch Vw row into registers for pred-blocks (independent of h_t)
    f32x4 vw0 = {0,0,0,0}, vw1 = {0,0,0,0}, vw2 = {0,0,0,0}, vw3 = {0,0,0,0};
    if (bid < D) {
        const f32x4* __restrict__ v = (const f32x4*)(Vw + (size_t)bid * H);
        vw0 = __builtin_nontemporal_load(&v[tid]);
        vw1 = __builtin_nontemporal_load(&v[tid + 256]);
        vw2 = __builtin_nontemporal_load(&v[tid + 512]);
        vw3 = __builtin_nontemporal_load(&v[tid + 768]);
    }
    __syncthreads();

    // ---- phase 1: one Uw row per wave ----
    const f32x4* __restrict__ u = (const f32x4*)(Uw + (size_t)row * H);
    float acc0 = 0.f, acc1 = 0.f;
    #pragma unroll 4
    for (int k = 0; k < 16; k += 2) {
        const int j0 = lane + k * 64;
        const int j1 = j0 + 64;
        f32x4 a0 = __builtin_nontemporal_load(&u[j0]);
        f32x4 b0 = s_h4[j0];
        f32x4 a1 = __builtin_nontemporal_load(&u[j1]);
        f32x4 b1 = s_h4[j1];
        acc0 += dot4(a0, b0);
        acc1 += dot4(a1, b1);
    }
    float acc = acc0 + acc1;

    const f32x4* __restrict__ w  = (const f32x4*)(Ww + (size_t)row * D);
    const f32x4* __restrict__ lv = (const f32x4*)line;
    if (lane < D / 4) {
        f32x4 a = __builtin_nontemporal_load(&w[lane]);
        acc += dot4(a, lv[lane]);
    }

    #pragma unroll
    for (int off = 32; off; off >>= 1)
        acc += __shfl_down(acc, off, 64);

    if (lane == 0) {
        float v = acc + Ub[row] + Wb[row];
        out[D + row] = 1.f / (1.f + expf(-v));
    }

    // ---- arrival: release h_t device-wide, then count in ----
    __threadfence();
    __syncthreads();
    if (tid == 0)
        atomicAdd(&cnt[(bid & (NCNT - 1)) * CSTRIDE], 1u);

    if (bid >= D) return;

    // ---- grid barrier spin (blocks 0..103 only) ----
    if (tid == 0) {
        for (;;) {
            unsigned s = 0;
            #pragma unroll
            for (int i = 0; i < NCNT; ++i)
                s += __hip_atomic_load(&cnt[i * CSTRIDE],
                                       __ATOMIC_RELAXED,
                                       __HIP_MEMORY_SCOPE_AGENT);
            if (s == NBLK) break;
            __builtin_amdgcn_s_sleep(8);
        }
    }
    __syncthreads();
    __threadfence();   // acquire: h_t now visible

    // ---- phase 2: pred[bid] = Vw[bid,:].h_t + Vb[bid] ----
    const f32x4* __restrict__ ht4 = (const f32x4*)(out + D);
    float p = dot4(vw0, ht4[tid])       + dot4(vw1, ht4[tid + 256])
            + dot4(vw2, ht4[tid + 512]) + dot4(vw3, ht4[tid + 768]);
    #pragma unroll
    for (int off = 32; off; off >>= 1)
        p += __shfl_down(p, off, 64);
    if (lane == 0) s_red[wave] = p;
    __syncthreads();

    // segment lookup (block-uniform)
    const int SEG[11] = {0, 13, 26, 39, 48, 52, 65, 78, 91, 100, 104};
    int sidx = 0;
    #pragma unroll
    for (int i = 1; i < 10; ++i)
        if (bid >= SEG[i]) sidx = i;
    const int a   = SEG[sidx];
    const int len = SEG[sidx + 1] - a;

    if (tid == 0) {
        float pr = s_red[0] + s_red[1] + s_red[2] + s_red[3] + Vb[bid];
        pred[bid * 32] = pr;          // own cache line -> no false sharing
        __threadfence();              // release pred
        unsigned old = atomicAdd(&segcnt[sidx * CSTRIDE], 1u);
        s_last = (old == (unsigned)(len - 1));
    }
    __syncthreads();

    // ---- phase 3: last block of each segment does its log_softmax ----
    if (s_last && wave == 0) {
        __threadfence();              // acquire other blocks' pred
        volatile const float* pp = pred;
        float x = (lane < len) ? pp[(a + lane) * 32] : -INFINITY;
        float m = x;
        #pragma unroll
        for (int off = 32; off; off >>= 1)
            m = fmaxf(m, __shfl_xor(m, off, 64));
        float e = (lane < len) ? expf(x - m) : 0.f;
        float ssum = e;
        #pragma unroll
        for (int off = 32; off; off >>= 1)
            ssum += __shfl_xor(ssum, off, 64);
        if (lane < len) out[a + lane] = x - m - logf(ssum);
    }
}

extern "C" void kernel_launch(void* const* d_in, const int* in_sizes, int n_in,
                              void* d_out, int out_size, void* d_ws, size_t ws_size,
                              hipStream_t stream) {
    const float* line   = (const float*)d_in[0];
    const float* hidden = (const float*)d_in[1];
    const float* Uw     = (const float*)d_in[2];
    const float* Ub     = (const float*)d_in[3];
    const float* Ww     = (const float*)d_in[4];
    const float* Wb     = (const float*)d_in[5];
    const float* Vw     = (const float*)d_in[6];
    const float* Vb     = (const float*)d_in[7];

    float* out = (float*)d_out;

    // ws layout: [0,4K) arrival counters; [4K,5.25K) seg counters;
    //            [8K,21K) padded pred. Zero the counter region each launch.
    unsigned* cnt    = (unsigned*)d_ws;
    unsigned* segcnt = (unsigned*)d_ws + 1024;
    float*    pred   = (float*)d_ws + 2048;

    hipMemsetAsync(d_ws, 0, 8192, stream);
    k_fused<<<NBLK, 256, 0, stream>>>(Uw, hidden, Ub, Ww, line, Wb, Vw, Vb,
                                      out, cnt, segcnt, pred);
}

// Round 7
// 25.749 us; speedup vs baseline: 4.8407x; 4.8407x over previous
//
#include <hip/hip_runtime.h>
#include <math.h>

#define H 4096
#define D 104
#define TCOLS 512
#define NTILES (H / TCOLS)        // 8 K-tiles per row

typedef float f32x4 __attribute__((ext_vector_type(4)));
typedef __attribute__((address_space(3))) unsigned int lds_u32;
typedef const __attribute__((address_space(1))) unsigned int glb_u32;

__device__ __forceinline__ float dot4(f32x4 a, f32x4 b) {
    return a.x * b.x + a.y * b.y + a.z * b.z + a.w * b.w;
}

// Kernel 1: h_t = sigmoid(Uw @ hidden + Ub + Ww @ line + Wb)
// 1024 blocks x 256 thr (4 waves), one Uw row per wave.
// Uw is staged via global_load_lds (width 16) into double-buffered 8 KB
// tiles: in-flight bytes live in the LDS queue instead of VGPRs, so
// 4 blocks/CU keep ~32 KB/CU in flight -> HBM-BW-bound, not latency-bound.
__global__ void __launch_bounds__(256, 4) k_hidden(
    const float* __restrict__ Uw, const float* __restrict__ hidden,
    const float* __restrict__ Ub, const float* __restrict__ Ww,
    const float* __restrict__ line, const float* __restrict__ Wb,
    float* __restrict__ h_out)
{
    __shared__ f32x4 s_h4[H / 4];          // 16 KB
    __shared__ float s_u[2][4 * TCOLS];    // 2 x 8 KB tiles (4 rows x 512)

    const int tid  = threadIdx.x;
    const int wave = tid >> 6;
    const int lane = tid & 63;
    const int row  = blockIdx.x * 4 + wave;

    // stage hidden to LDS (1024 f32x4 / 256 threads = 4 each)
    const f32x4* __restrict__ hv = (const f32x4*)hidden;
    #pragma unroll
    for (int i = tid; i < H / 4; i += 256)
        s_h4[i] = hv[i];

    const float* __restrict__ grow = Uw + (size_t)row * H;

    // stage one 512-col slice of this wave's row: 2 x 1KB wave passes.
    // LDS dest = wave-uniform base + lane*16 (matches HW semantics).
    #define STAGE(t, buf)                                                     \
        do {                                                                  \
            const float* g0 = grow + (t) * TCOLS + 4 * lane;                  \
            __builtin_amdgcn_global_load_lds(                                 \
                (glb_u32*)g0,                                                 \
                (lds_u32*)&s_u[buf][wave * TCOLS + 4 * lane], 16, 0, 0);      \
            const float* g1 = g0 + 256;                                       \
            __builtin_amdgcn_global_load_lds(                                 \
                (glb_u32*)g1,                                                 \
                (lds_u32*)&s_u[buf][wave * TCOLS + 256 + 4 * lane], 16, 0, 0);\
        } while (0)

    STAGE(0, 0);
    __syncthreads();   // drains vmcnt: tile 0 + hidden staged

    float acc0 = 0.f, acc1 = 0.f;
    #pragma unroll
    for (int t = 0; t < NTILES; ++t) {
        if (t + 1 < NTILES)
            STAGE(t + 1, (t + 1) & 1);

        const int c4 = t * (TCOLS / 4);
        f32x4 u0 = *(const f32x4*)&s_u[t & 1][wave * TCOLS + 4 * lane];
        f32x4 u1 = *(const f32x4*)&s_u[t & 1][wave * TCOLS + 256 + 4 * lane];
        acc0 += dot4(u0, s_h4[c4 + lane]);
        acc1 += dot4(u1, s_h4[c4 + 64 + lane]);

        // barrier: all waves done with buf[t&1]; compiler-inserted
        // vmcnt(0) drain means tile t+1 has landed.
        __syncthreads();
    }
    float acc = acc0 + acc1;

    // Ww @ line tail: 26 f32x4 per row
    const f32x4* __restrict__ w  = (const f32x4*)(Ww + (size_t)row * D);
    const f32x4* __restrict__ lv = (const f32x4*)line;
    if (lane < D / 4) {
        f32x4 a = __builtin_nontemporal_load(&w[lane]);
        acc += dot4(a, lv[lane]);
    }

    #pragma unroll
    for (int off = 32; off; off >>= 1)
        acc += __shfl_down(acc, off, 64);

    if (lane == 0) {
        float v = acc + Ub[row] + Wb[row];
        h_out[row] = 1.f / (1.f + expf(-v));
    }
}

// Kernel 2a: pred[d] = Vw[d,:] . h_t + Vb[d], one block per row d.
__global__ void __launch_bounds__(256) k_pred_rows(
    const float* __restrict__ Vw, const float* __restrict__ h_t,
    const float* __restrict__ Vb, float* __restrict__ pred)
{
    __shared__ float r[4];
    const int d    = blockIdx.x;
    const int tid  = threadIdx.x;
    const int wave = tid >> 6;
    const int lane = tid & 63;

    const f32x4* __restrict__ v  = (const f32x4*)(Vw + (size_t)d * H);
    const f32x4* __restrict__ hv = (const f32x4*)h_t;

    float acc = 0.f;
    #pragma unroll
    for (int j4 = tid; j4 < H / 4; j4 += 256) {   // 4 iterations
        f32x4 x = __builtin_nontemporal_load(&v[j4]);
        f32x4 y = hv[j4];
        acc += dot4(x, y);
    }
    #pragma unroll
    for (int off = 32; off; off >>= 1)
        acc += __shfl_down(acc, off, 64);
    if (lane == 0) r[wave] = acc;
    __syncthreads();
    if (tid == 0)
        pred[d] = r[0] + r[1] + r[2] + r[3] + Vb[d];
}

// Kernel 2b: 10 independent segmented log_softmaxes; wave s = segment s.
__global__ void __launch_bounds__(640) k_logsoftmax(
    const float* __restrict__ pred, float* __restrict__ out)
{
    const int seg_a[11] = {0, 13, 26, 39, 48, 52, 65, 78, 91, 100, 104};
    const int s    = threadIdx.x >> 6;
    const int lane = threadIdx.x & 63;
    const int a    = seg_a[s];
    const int len  = seg_a[s + 1] - a;

    float x = (lane < len) ? pred[a + lane] : -INFINITY;
    float m = x;
    #pragma unroll
    for (int off = 32; off; off >>= 1)
        m = fmaxf(m, __shfl_xor(m, off, 64));
    float e = (lane < len) ? expf(x - m) : 0.f;
    float ssum = e;
    #pragma unroll
    for (int off = 32; off; off >>= 1)
        ssum += __shfl_xor(ssum, off, 64);
    if (lane < len) out[a + lane] = x - m - logf(ssum);
}

extern "C" void kernel_launch(void* const* d_in, const int* in_sizes, int n_in,
                              void* d_out, int out_size, void* d_ws, size_t ws_size,
                              hipStream_t stream) {
    const float* line   = (const float*)d_in[0];
    const float* hidden = (const float*)d_in[1];
    const float* Uw     = (const float*)d_in[2];
    const float* Ub     = (const float*)d_in[3];
    const float* Ww     = (const float*)d_in[4];
    const float* Wb     = (const float*)d_in[5];
    const float* Vw     = (const float*)d_in[6];
    const float* Vb     = (const float*)d_in[7];

    float* out  = (float*)d_out;      // [0:104) pred_logsoft, [104:4200) h_t
    float* h_t  = out + D;
    float* pred = (float*)d_ws;       // scratch: 104 floats

    k_hidden<<<H / 4, 256, 0, stream>>>(Uw, hidden, Ub, Ww, line, Wb, h_t);
    k_pred_rows<<<D, 256, 0, stream>>>(Vw, h_t, Vb, pred);
    k_logsoftmax<<<1, 640, 0, stream>>>(pred, out);
}

// Round 8
// 20.601 us; speedup vs baseline: 6.0502x; 1.2499x over previous
//
#include <hip/hip_runtime.h>
#include <math.h>

#define H 4096
#define D 104
#define CSTRIDE 32        // 32 uints = 128 B between counters / pred slots

typedef float f32x4 __attribute__((ext_vector_type(4)));

__device__ __forceinline__ float dot4(f32x4 a, f32x4 b) {
    return a.x * b.x + a.y * b.y + a.z * b.z + a.w * b.w;
}

// Kernel 1: h_t = sigmoid(Uw @ hidden + Ub + Ww @ line + Wb)
// grid = H/4 blocks of 256 threads (4 waves); one row per wave. (R4 form —
// proven 20.86 baseline component.) Block 0 additionally zeroes the segment
// counters for kernel 2 via agent-scope stores (kernel boundary orders them).
__global__ void __launch_bounds__(256) k_hidden(
    const float* __restrict__ Uw, const float* __restrict__ hidden,
    const float* __restrict__ Ub, const float* __restrict__ Ww,
    const float* __restrict__ line, const float* __restrict__ Wb,
    float* __restrict__ h_out, unsigned* __restrict__ segcnt)
{
    __shared__ f32x4 s_h4[H / 4];          // 16 KB

    const int tid  = threadIdx.x;
    const int wave = tid >> 6;
    const int lane = tid & 63;
    const int row  = blockIdx.x * 4 + wave;

    if (blockIdx.x == 0 && tid < 10)
        __hip_atomic_store(&segcnt[tid * CSTRIDE], 0u,
                           __ATOMIC_RELAXED, __HIP_MEMORY_SCOPE_AGENT);

    // cooperative stage of hidden: 1024 float4 / 256 threads = 4 each
    const f32x4* __restrict__ hv = (const f32x4*)hidden;
    #pragma unroll
    for (int i = tid; i < H / 4; i += 256)
        s_h4[i] = hv[i];
    __syncthreads();

    const f32x4* __restrict__ u = (const f32x4*)(Uw + (size_t)row * H);

    float acc0 = 0.f, acc1 = 0.f;
    #pragma unroll 4
    for (int k = 0; k < 16; k += 2) {
        const int j0 = lane + k * 64;
        const int j1 = j0 + 64;
        f32x4 a0 = __builtin_nontemporal_load(&u[j0]);
        f32x4 b0 = s_h4[j0];
        f32x4 a1 = __builtin_nontemporal_load(&u[j1]);
        f32x4 b1 = s_h4[j1];
        acc0 += dot4(a0, b0);
        acc1 += dot4(a1, b1);
    }
    float acc = acc0 + acc1;

    // Ww @ line tail: D=104 -> 26 float4 per row
    const f32x4* __restrict__ w  = (const f32x4*)(Ww + (size_t)row * D);
    const f32x4* __restrict__ lv = (const f32x4*)line;
    if (lane < D / 4) {
        f32x4 a = __builtin_nontemporal_load(&w[lane]);
        acc += dot4(a, lv[lane]);
    }

    #pragma unroll
    for (int off = 32; off; off >>= 1)
        acc += __shfl_down(acc, off, 64);

    if (lane == 0) {
        float v = acc + Ub[row] + Wb[row];
        h_out[row] = 1.f / (1.f + expf(-v));
    }
}

// Kernel 2 (merged): one block per pred row. Each block computes
// pred[bid] = Vw[bid,:].h_t + Vb[bid], publishes it agent-scope, bumps its
// segment counter; the LAST-arriving block of each segment (atomic return
// value — no spinning, no co-residency assumption) does the log_softmax.
__global__ void __launch_bounds__(256) k_pred(
    const float* __restrict__ Vw, const float* __restrict__ h_t,
    const float* __restrict__ Vb, float* __restrict__ out,
    unsigned* __restrict__ segcnt, float* __restrict__ pred)
{
    __shared__ float r[4];
    __shared__ int s_last;
    const int bid  = blockIdx.x;
    const int tid  = threadIdx.x;
    const int wave = tid >> 6;
    const int lane = tid & 63;

    const f32x4* __restrict__ v  = (const f32x4*)(Vw + (size_t)bid * H);
    const f32x4* __restrict__ hv = (const f32x4*)h_t;

    float acc = 0.f;
    #pragma unroll
    for (int j4 = tid; j4 < H / 4; j4 += 256) {   // 4 iterations
        f32x4 x = __builtin_nontemporal_load(&v[j4]);
        f32x4 y = hv[j4];
        acc += dot4(x, y);
    }
    #pragma unroll
    for (int off = 32; off; off >>= 1)
        acc += __shfl_down(acc, off, 64);
    if (lane == 0) r[wave] = acc;
    __syncthreads();

    // segment lookup (block-uniform)
    const int SEG[11] = {0, 13, 26, 39, 48, 52, 65, 78, 91, 100, 104};
    int sidx = 0;
    #pragma unroll
    for (int i = 1; i < 10; ++i)
        if (bid >= SEG[i]) sidx = i;
    const int a   = SEG[sidx];
    const int len = SEG[sidx + 1] - a;

    if (tid == 0) {
        float pr = r[0] + r[1] + r[2] + r[3] + Vb[bid];
        __hip_atomic_store(&pred[bid * CSTRIDE], pr,
                           __ATOMIC_RELAXED, __HIP_MEMORY_SCOPE_AGENT);
        asm volatile("s_waitcnt vmcnt(0)" ::: "memory");  // pred at LLC
        unsigned old = __hip_atomic_fetch_add(&segcnt[sidx * CSTRIDE], 1u,
                                              __ATOMIC_RELAXED,
                                              __HIP_MEMORY_SCOPE_AGENT);
        s_last = (old == (unsigned)(len - 1));
    }
    __syncthreads();

    // last-arriving block of the segment: all peers' preds are at the LLC
    if (s_last && wave == 0) {
        float x = -INFINITY;
        if (lane < len)
            x = __hip_atomic_load(&pred[(a + lane) * CSTRIDE],
                                  __ATOMIC_RELAXED, __HIP_MEMORY_SCOPE_AGENT);
        float m = x;
        #pragma unroll
        for (int off = 32; off; off >>= 1)
            m = fmaxf(m, __shfl_xor(m, off, 64));
        float e = (lane < len) ? expf(x - m) : 0.f;
        float ssum = e;
        #pragma unroll
        for (int off = 32; off; off >>= 1)
            ssum += __shfl_xor(ssum, off, 64);
        if (lane < len) out[a + lane] = x - m - logf(ssum);
    }
}

extern "C" void kernel_launch(void* const* d_in, const int* in_sizes, int n_in,
                              void* d_out, int out_size, void* d_ws, size_t ws_size,
                              hipStream_t stream) {
    const float* line   = (const float*)d_in[0];
    const float* hidden = (const float*)d_in[1];
    const float* Uw     = (const float*)d_in[2];
    const float* Ub     = (const float*)d_in[3];
    const float* Ww     = (const float*)d_in[4];
    const float* Wb     = (const float*)d_in[5];
    const float* Vw     = (const float*)d_in[6];
    const float* Vb     = (const float*)d_in[7];

    float* out = (float*)d_out;       // [0:104) pred_logsoft, [104:4200) h_t
    float* h_t = out + D;

    unsigned* segcnt = (unsigned*)d_ws;            // 10 counters, 128B stride
    float*    pred   = (float*)d_ws + 1024;        // 104 slots, 128B stride

    k_hidden<<<H / 4, 256, 0, stream>>>(Uw, hidden, Ub, Ww, line, Wb, h_t, segcnt);
    k_pred<<<D, 256, 0, stream>>>(Vw, h_t, Vb, out, segcnt, pred);
}

// Round 9
// 20.587 us; speedup vs baseline: 6.0545x; 1.0007x over previous
//
#include <hip/hip_runtime.h>
#include <math.h>

#define H 4096
#define D 104
#define CSTRIDE 32        // 32 uints = 128 B between counters / pred slots

typedef float f32x4 __attribute__((ext_vector_type(4)));

__device__ __forceinline__ float dot4(f32x4 a, f32x4 b) {
    return a.x * b.x + a.y * b.y + a.z * b.z + a.w * b.w;
}

// Kernel 1: h_t = sigmoid(Uw @ hidden + Ub + Ww @ line + Wb)
// v2: HALF-row per wave. 2048 blocks x 4 waves = 8 blocks/CU = 32 waves/CU
// (100% occupancy), and 8 fully-unrolled nontemporal loads per wave issued
// back-to-back (8 KB in flight per wave, ~256 KB/CU) -> latency-proof.
// The two half-row partials combine through LDS.
__global__ void __launch_bounds__(256, 8) k_hidden(
    const float* __restrict__ Uw, const float* __restrict__ hidden,
    const float* __restrict__ Ub, const float* __restrict__ Ww,
    const float* __restrict__ line, const float* __restrict__ Wb,
    float* __restrict__ h_out, unsigned* __restrict__ segcnt)
{
    __shared__ f32x4 s_h4[H / 4];          // 16 KB
    __shared__ float s_part[4];

    const int tid  = threadIdx.x;
    const int wave = tid >> 6;
    const int lane = tid & 63;
    const int g    = blockIdx.x * 4 + wave;   // global wave id, 0..8191
    const int row  = g >> 1;
    const int half = g & 1;

    if (blockIdx.x == 0 && tid < 10)
        __hip_atomic_store(&segcnt[tid * CSTRIDE], 0u,
                           __ATOMIC_RELAXED, __HIP_MEMORY_SCOPE_AGENT);

    // stage hidden to LDS (1024 f32x4 / 256 threads = 4 each)
    const f32x4* __restrict__ hv = (const f32x4*)hidden;
    #pragma unroll
    for (int i = tid; i < H / 4; i += 256)
        s_h4[i] = hv[i];
    __syncthreads();

    // this wave's half-row: 512 f32x4 starting at column-f32x4 c0
    const int c0 = half * (H / 8);            // 0 or 512 (f32x4 units)
    const f32x4* __restrict__ u = (const f32x4*)(Uw + (size_t)row * H) + c0;

    // issue all 8 streaming loads back-to-back (VMEM in-order, 8 deep)
    f32x4 a0 = __builtin_nontemporal_load(&u[lane]);
    f32x4 a1 = __builtin_nontemporal_load(&u[lane + 64]);
    f32x4 a2 = __builtin_nontemporal_load(&u[lane + 128]);
    f32x4 a3 = __builtin_nontemporal_load(&u[lane + 192]);
    f32x4 a4 = __builtin_nontemporal_load(&u[lane + 256]);
    f32x4 a5 = __builtin_nontemporal_load(&u[lane + 320]);
    f32x4 a6 = __builtin_nontemporal_load(&u[lane + 384]);
    f32x4 a7 = __builtin_nontemporal_load(&u[lane + 448]);

    float acc0, acc1;
    {
        const f32x4* hb = s_h4 + c0;
        acc0  = dot4(a0, hb[lane]);
        acc1  = dot4(a1, hb[lane + 64]);
        acc0 += dot4(a2, hb[lane + 128]);
        acc1 += dot4(a3, hb[lane + 192]);
        acc0 += dot4(a4, hb[lane + 256]);
        acc1 += dot4(a5, hb[lane + 320]);
        acc0 += dot4(a6, hb[lane + 384]);
        acc1 += dot4(a7, hb[lane + 448]);
    }
    float acc = acc0 + acc1;

    // Ww @ line tail (26 f32x4/row): folded into the half==0 wave
    if (half == 0 && lane < D / 4) {
        const f32x4* __restrict__ w  = (const f32x4*)(Ww + (size_t)row * D);
        const f32x4* __restrict__ lv = (const f32x4*)line;
        f32x4 a = __builtin_nontemporal_load(&w[lane]);
        acc += dot4(a, lv[lane]);
    }

    #pragma unroll
    for (int off = 32; off; off >>= 1)
        acc += __shfl_down(acc, off, 64);

    if (lane == 0) s_part[wave] = acc;
    __syncthreads();

    // half==0 wave of each row finishes: combine halves, bias, sigmoid
    if (half == 0 && lane == 0) {
        float v = s_part[wave] + s_part[wave + 1] + Ub[row] + Wb[row];
        h_out[row] = 1.f / (1.f + expf(-v));
    }
}

// Kernel 2 (merged, unchanged from R8): one block per pred row; last-arriving
// block per segment does the log_softmax (atomic return value, no spinning).
__global__ void __launch_bounds__(256) k_pred(
    const float* __restrict__ Vw, const float* __restrict__ h_t,
    const float* __restrict__ Vb, float* __restrict__ out,
    unsigned* __restrict__ segcnt, float* __restrict__ pred)
{
    __shared__ float r[4];
    __shared__ int s_last;
    const int bid  = blockIdx.x;
    const int tid  = threadIdx.x;
    const int wave = tid >> 6;
    const int lane = tid & 63;

    const f32x4* __restrict__ v  = (const f32x4*)(Vw + (size_t)bid * H);
    const f32x4* __restrict__ hv = (const f32x4*)h_t;

    float acc = 0.f;
    #pragma unroll
    for (int j4 = tid; j4 < H / 4; j4 += 256) {   // 4 iterations
        f32x4 x = __builtin_nontemporal_load(&v[j4]);
        f32x4 y = hv[j4];
        acc += dot4(x, y);
    }
    #pragma unroll
    for (int off = 32; off; off >>= 1)
        acc += __shfl_down(acc, off, 64);
    if (lane == 0) r[wave] = acc;
    __syncthreads();

    // segment lookup (block-uniform)
    const int SEG[11] = {0, 13, 26, 39, 48, 52, 65, 78, 91, 100, 104};
    int sidx = 0;
    #pragma unroll
    for (int i = 1; i < 10; ++i)
        if (bid >= SEG[i]) sidx = i;
    const int a   = SEG[sidx];
    const int len = SEG[sidx + 1] - a;

    if (tid == 0) {
        float pr = r[0] + r[1] + r[2] + r[3] + Vb[bid];
        __hip_atomic_store(&pred[bid * CSTRIDE], pr,
                           __ATOMIC_RELAXED, __HIP_MEMORY_SCOPE_AGENT);
        asm volatile("s_waitcnt vmcnt(0)" ::: "memory");  // pred at LLC
        unsigned old = __hip_atomic_fetch_add(&segcnt[sidx * CSTRIDE], 1u,
                                              __ATOMIC_RELAXED,
                                              __HIP_MEMORY_SCOPE_AGENT);
        s_last = (old == (unsigned)(len - 1));
    }
    __syncthreads();

    // last-arriving block of the segment: all peers' preds are at the LLC
    if (s_last && wave == 0) {
        float x = -INFINITY;
        if (lane < len)
            x = __hip_atomic_load(&pred[(a + lane) * CSTRIDE],
                                  __ATOMIC_RELAXED, __HIP_MEMORY_SCOPE_AGENT);
        float m = x;
        #pragma unroll
        for (int off = 32; off; off >>= 1)
            m = fmaxf(m, __shfl_xor(m, off, 64));
        float e = (lane < len) ? expf(x - m) : 0.f;
        float ssum = e;
        #pragma unroll
        for (int off = 32; off; off >>= 1)
            ssum += __shfl_xor(ssum, off, 64);
        if (lane < len) out[a + lane] = x - m - logf(ssum);
    }
}

extern "C" void kernel_launch(void* const* d_in, const int* in_sizes, int n_in,
                              void* d_out, int out_size, void* d_ws, size_t ws_size,
                              hipStream_t stream) {
    const float* line   = (const float*)d_in[0];
    const float* hidden = (const float*)d_in[1];
    const float* Uw     = (const float*)d_in[2];
    const float* Ub     = (const float*)d_in[3];
    const float* Ww     = (const float*)d_in[4];
    const float* Wb     = (const float*)d_in[5];
    const float* Vw     = (const float*)d_in[6];
    const float* Vb     = (const float*)d_in[7];

    float* out = (float*)d_out;       // [0:104) pred_logsoft, [104:4200) h_t
    float* h_t = out + D;

    unsigned* segcnt = (unsigned*)d_ws;            // 10 counters, 128B stride
    float*    pred   = (float*)d_ws + 1024;        // 104 slots, 128B stride

    k_hidden<<<H / 2, 256, 0, stream>>>(Uw, hidden, Ub, Ww, line, Wb, h_t, segcnt);
    k_pred<<<D, 256, 0, stream>>>(Vw, h_t, Vb, out, segcnt, pred);
}